// Round 17
// baseline (122.372 us; speedup 1.0000x reference)
//
#include <hip/hip_runtime.h>
#include <hip/hip_bf16.h>
#include <math.h>

#define NF 64
#define NC 16
#define MAIN_BLOCKS 256
#define MAIN_WAVES  13                 // 832 thr; 3328 waves vs 3125 tiles
#define TPW 4                          // 16-sample subtiles per wave (64 samples)

typedef __bf16 bf16x8 __attribute__((ext_vector_type(8)));
typedef float f32x4 __attribute__((ext_vector_type(4)));
typedef unsigned int u32;

// async global->LDS, 16B/lane. LDS dest = wave-uniform base (HW adds lane*16).
__device__ __forceinline__ void stage16(const void* gsrc, void* ldst) {
    __builtin_amdgcn_global_load_lds(
        (const __attribute__((address_space(1))) u32*)gsrc,
        (__attribute__((address_space(3))) u32*)ldst,
        16, 0, 0);
}

// ---------------------------------------------------------------------------
// Fused kernel v17: producer/consumer blocks, one launch.
//  - 256 blocks x 832 thr, 135232B LDS -> exactly 1 block/CU and the whole
//    grid is co-resident (grid == CU count) -> spin-wait is deadlock-free.
//  - Blocks 0..15: v8 4-wave Cholesky+inverse (waves 4..12 ride the
//    barriers), write swizzled g/t/Cc to ws, __threadfence + atomicAdd(flag).
//  - Blocks 16..255: prefetch x fragments (overlaps the precompute head),
//    spin on flag (volatile + s_sleep).
//  - All blocks: acquire fence, stage16 G (128KB), nt/cc to LDS, then the
//    v16 inner loop (triangular skip, stagger, defer-max LSE) unchanged.
//  - LDS is a union: precompute scratch (35KB) reused as gbuf (128KB).
//  - flag zeroed per call via hipMemsetAsync (deterministic across replays).
// ---------------------------------------------------------------------------
__global__ __launch_bounds__(832) void gmm_fused(
    const float* __restrict__ cov,
    const float* __restrict__ means,
    const float* __restrict__ weights,
    const float* __restrict__ data,
    __hip_bfloat16* __restrict__ g,       // ws: swizzled bf16 G [NC][8192 B]
    float* __restrict__ t,                // ws
    float* __restrict__ Cc,               // ws
    unsigned int* __restrict__ flag,      // ws, pre-zeroed
    float* __restrict__ partials,
    int nTiles, int N, int totalWaves)
{
    __shared__ __align__(16) char smem[135232];
    // main-phase aliases
    char*  gbuf   = smem;                          // 131072 B
    float* nt_lds = (float*)(smem + 131072);       // 4096 B
    float* cc_lds = (float*)(smem + 131072 + 4096);// 64 B
    // precompute-phase aliases (dead before gbuf is written)
    float* LTb  = (float*)smem;                    // [64][68] = 17408 B
    float* Xsb  = (float*)(smem + 17408);          // [64][65] = 16640 B
    float* wb2b = (float*)(smem + 34048);          // [2][68]  = 544 B
    float* gw2b = (float*)(smem + 34592);          // [2][68]  = 544 B

    const int bid  = blockIdx.x;
    const int tidx = threadIdx.x;
    const int w    = tidx >> 6;
    const int lane = tidx & 63;
    const int l15  = lane & 15;
    const int lg   = lane >> 4;
    const bool isPre = (bid < NC);

    const int gid = bid * MAIN_WAVES + w;
    const bool haveTile = (gid < nTiles);

    bf16x8 xf[TPW][2];
    auto loadx = [&](long base) {
        #pragma unroll
        for (int st = 0; st < TPW; ++st) {
            long row = base + st * 16 + l15;
            if (row > (long)N - 1) row = (long)N - 1;
            const float* xp = data + row * NF + lg * 8;
            float4 a0 = *(const float4*)(xp);
            float4 a1 = *(const float4*)(xp + 4);
            float4 b0 = *(const float4*)(xp + 32);
            float4 b1 = *(const float4*)(xp + 36);
            bf16x8 f0, f1;
            f0[0] = (__bf16)a0.x; f0[1] = (__bf16)a0.y;
            f0[2] = (__bf16)a0.z; f0[3] = (__bf16)a0.w;
            f0[4] = (__bf16)a1.x; f0[5] = (__bf16)a1.y;
            f0[6] = (__bf16)a1.z; f0[7] = (__bf16)a1.w;
            f1[0] = (__bf16)b0.x; f1[1] = (__bf16)b0.y;
            f1[2] = (__bf16)b0.z; f1[3] = (__bf16)b0.w;
            f1[4] = (__bf16)b1.x; f1[5] = (__bf16)b1.y;
            f1[6] = (__bf16)b1.z; f1[7] = (__bf16)b1.w;
            xf[st][0] = f0;
            xf[st][1] = f1;
        }
    };

    if (!isPre && haveTile)
        loadx((long)gid * (TPW * 16));   // overlaps the precompute head

    // ================= producer phase (blocks 0..15) =================
    if (isPre) {
        const int k = bid;
        const int c = lane;

        float a_loc[16], rsq_loc[16];
        float logdiag = 0.0f;
        if (w < 4) {
            const float* src = cov + (long)k * NF * NF + (w * 16) * NF + c;
            #pragma unroll
            for (int r = 0; r < 16; ++r)
                a_loc[r] = src[r * NF];
        }

        // Cholesky: 4 rolled phases x 16 unrolled steps (v8)
        #pragma unroll 1
        for (int q = 0; q < 4; ++q) {
            #pragma unroll
            for (int jj = 0; jj < 16; ++jj) {
                float* wb = wb2b + (jj & 1) * 68;
                if (w == q) wb[c] = a_loc[jj];
                __syncthreads();
                const int j = q * 16 + jj;
                if (w < 4) {
                    float ajc = wb[c];
                    float d   = wb[j];
                    float sq  = sqrtf(d);
                    float rsq = __builtin_amdgcn_rcpf(sq);
                    float rd  = __builtin_amdgcn_rcpf(d);
                    logdiag += 0.5f * __logf(d);
                    if (w == q) rsq_loc[jj] = rsq;
                    if (w == 0) LTb[j * 68 + c] = ajc * rsq;   // col j of L
                    float beta = ajc * rd;
                    const float4* wv = (const float4*)(wb + w * 16);
                    #pragma unroll
                    for (int rr = 0; rr < 16; rr += 4) {
                        float4 v = wv[rr >> 2];
                        a_loc[rr]     = fmaf(-v.x, beta, a_loc[rr]);
                        a_loc[rr + 1] = fmaf(-v.y, beta, a_loc[rr + 1]);
                        a_loc[rr + 2] = fmaf(-v.z, beta, a_loc[rr + 2]);
                        a_loc[rr + 3] = fmaf(-v.w, beta, a_loc[rr + 3]);
                    }
                }
            }
        }

        // substitution: S = I, publish G row i at step i
        float s_loc[16];
        if (w < 4) {
            #pragma unroll
            for (int r = 0; r < 16; ++r)
                s_loc[r] = (w * 16 + r == c) ? 1.0f : 0.0f;
        }
        #pragma unroll 1
        for (int q = 0; q < 4; ++q) {
            #pragma unroll
            for (int ii = 0; ii < 16; ++ii) {
                const int i = q * 16 + ii;
                float* gw = gw2b + (ii & 1) * 68;
                if (w == q) {
                    float gv = s_loc[ii] * rsq_loc[ii];
                    gw[c] = gv;
                    Xsb[i * 65 + c] = gv;
                }
                __syncthreads();
                if (w < 4) {
                    float gc = gw[c];
                    const float4* lv4 = (const float4*)(LTb + i * 68 + w * 16);
                    #pragma unroll
                    for (int rr = 0; rr < 16; rr += 4) {
                        float4 v = lv4[rr >> 2];
                        s_loc[rr]     = fmaf(-v.x, gc, s_loc[rr]);
                        s_loc[rr + 1] = fmaf(-v.y, gc, s_loc[rr + 1]);
                        s_loc[rr + 2] = fmaf(-v.z, gc, s_loc[rr + 2]);
                        s_loc[rr + 3] = fmaf(-v.w, gc, s_loc[rr + 3]);
                    }
                }
            }
        }
        __syncthreads();

        // g row c (XOR-swizzled), t, Cc
        if (w < 4) {
            __hip_bfloat16* grow = g + ((long)(k * NF + c)) * NF;
            #pragma unroll
            for (int h = 0; h < 2; ++h) {
                int jb = w * 2 + h;
                bf16x8 v;
                #pragma unroll
                for (int u = 0; u < 8; ++u)
                    v[u] = (__bf16)Xsb[c * 65 + jb * 8 + u];
                *(bf16x8*)(grow + ((jb ^ (c & 7)) * 8)) = v;
            }
        }
        if (w == 0) {
            const float* mu = means + k * NF;
            float a0 = 0.0f, a1 = 0.0f;
            #pragma unroll
            for (int j = 0; j < NF; j += 2) {
                a0 = fmaf(Xsb[j * 65 + c],       mu[j],     a0);
                a1 = fmaf(Xsb[(j + 1) * 65 + c], mu[j + 1], a1);
            }
            t[k * NF + c] = a0 + a1;
            if (c == 0)
                Cc[k] = __logf(weights[k]) - 0.5f * (float)NF * 1.8378770664093453f - logdiag;
        }
        __syncthreads();                       // all stores issued (vmcnt drained)
        if (tidx == 0) {
            __threadfence();                   // device-scope release (L2 wb)
            atomicAdd(flag, 1u);
        }
    }

    // ================= consumer sync =================
    if (tidx == 0) {
        volatile unsigned int* vf = (volatile unsigned int*)flag;
        while (*vf < (unsigned int)NC)
            __builtin_amdgcn_s_sleep(2);
    }
    __syncthreads();
    __threadfence();                           // acquire: invalidate stale lines

    // ================= stage + main loop (v16 body) =================
    for (int i = w; i < NC; i += MAIN_WAVES) {
        const char* src = (const char*)g + (size_t)i * 8192;
        char* dst = gbuf + (size_t)i * 8192;
        #pragma unroll
        for (int u = 0; u < 8; ++u)
            stage16(src + u * 1024 + lane * 16, dst + u * 1024);
    }
    for (int i = tidx; i < NC * NF; i += 64 * MAIN_WAVES) nt_lds[i] = -t[i];
    if (tidx < NC) cc_lds[tidx] = Cc[tidx];

    if (isPre && haveTile)
        loadx((long)gid * (TPW * 16));

    int offA[4], offB[4];
    #pragma unroll
    for (int rc = 0; rc < 4; ++rc) {
        int row = rc * 16 + l15;
        offA[rc] = row * 128 + ((lg       ^ (l15 & 7)) * 16);
        offB[rc] = row * 128 + (((lg + 4) ^ (l15 & 7)) * 16);
    }

    __syncthreads();   // G + t staged

    float wavePartial = 0.0f;

    #pragma unroll 1
    for (int tile = gid; tile < nTiles; tile += totalWaves) {
        const long base = (long)tile * (TPW * 16);
        if (tile != gid) loadx(base);          // cold continuation path

        float m[TPW], s[TPW];
        #pragma unroll
        for (int st = 0; st < TPW; ++st) { m[st] = -INFINITY; s[st] = 0.0f; }

        #pragma unroll 2
        for (int ii = 0; ii < NC; ++ii) {
            const int kk = (ii + w) & (NC - 1);      // per-wave stagger
            float mah[TPW];
            #pragma unroll
            for (int st = 0; st < TPW; ++st) mah[st] = 0.0f;

            const char* gk = gbuf + kk * 8192;
            const float* ntk = &nt_lds[kk * NF];

            // rc 0,1: rows 0..31 of lower-tri G -> cols 32..63 are ZERO
            #pragma unroll
            for (int rc = 0; rc < 2; ++rc) {
                bf16x8 ga = *(const bf16x8*)(gk + offA[rc]);
                f32x4 ntv = *(const f32x4*)(ntk + rc * 16 + lg * 4);
                #pragma unroll
                for (int st = 0; st < TPW; ++st) {
                    f32x4 acc = ntv;
                    acc = __builtin_amdgcn_mfma_f32_16x16x32_bf16(ga, xf[st][0], acc, 0, 0, 0);
                    mah[st] = fmaf(acc[0], acc[0], mah[st]);
                    mah[st] = fmaf(acc[1], acc[1], mah[st]);
                    mah[st] = fmaf(acc[2], acc[2], mah[st]);
                    mah[st] = fmaf(acc[3], acc[3], mah[st]);
                }
            }
            // rc 2,3: full rows
            #pragma unroll
            for (int rc = 2; rc < 4; ++rc) {
                bf16x8 ga = *(const bf16x8*)(gk + offA[rc]);
                bf16x8 gb = *(const bf16x8*)(gk + offB[rc]);
                f32x4 ntv = *(const f32x4*)(ntk + rc * 16 + lg * 4);
                #pragma unroll
                for (int st = 0; st < TPW; ++st) {
                    f32x4 acc = ntv;
                    acc = __builtin_amdgcn_mfma_f32_16x16x32_bf16(ga, xf[st][0], acc, 0, 0, 0);
                    acc = __builtin_amdgcn_mfma_f32_16x16x32_bf16(gb, xf[st][1], acc, 0, 0, 0);
                    mah[st] = fmaf(acc[0], acc[0], mah[st]);
                    mah[st] = fmaf(acc[1], acc[1], mah[st]);
                    mah[st] = fmaf(acc[2], acc[2], mah[st]);
                    mah[st] = fmaf(acc[3], acc[3], mah[st]);
                }
            }

            // defer-max logsumexp
            float Ck = cc_lds[kk];
            float wlp[TPW];
            float dmax = -INFINITY;
            #pragma unroll
            for (int st = 0; st < TPW; ++st) {
                float v = mah[st];
                v += __shfl_xor(v, 16);
                v += __shfl_xor(v, 32);
                wlp[st] = fmaf(-0.5f, v, Ck);
                dmax = fmaxf(dmax, wlp[st] - m[st]);
            }
            if (__any(dmax > 60.0f)) {
                #pragma unroll
                for (int st = 0; st < TPW; ++st) {
                    float mn = fmaxf(m[st], wlp[st]);
                    s[st] = s[st] * __expf(m[st] - mn) + __expf(wlp[st] - mn);
                    m[st] = mn;
                }
            } else {
                #pragma unroll
                for (int st = 0; st < TPW; ++st)
                    s[st] += __expf(wlp[st] - m[st]);
            }
        }

        if (lg == 0) {
            #pragma unroll
            for (int st = 0; st < TPW; ++st) {
                long sid = base + st * 16 + l15;
                if (sid < (long)N)
                    wavePartial += m[st] + __logf(s[st]);
            }
        }
    }

    #pragma unroll
    for (int off = 1; off < 64; off <<= 1)
        wavePartial += __shfl_xor(wavePartial, off);
    if (lane == 0)
        partials[gid] = wavePartial;
}

// ---------------------------------------------------------------------------
// Final deterministic reduction over per-wave partials.
// ---------------------------------------------------------------------------
__global__ __launch_bounds__(256) void gmm_reduce(
    const float* __restrict__ partials, int n, float* __restrict__ out)
{
    float s = 0.0f;
    for (int i = threadIdx.x; i < n; i += 256)
        s += partials[i];
    #pragma unroll
    for (int off = 1; off < 64; off <<= 1)
        s += __shfl_xor(s, off);
    __shared__ float sm[4];
    const int wave = threadIdx.x >> 6;
    const int lane = threadIdx.x & 63;
    if (lane == 0) sm[wave] = s;
    __syncthreads();
    if (threadIdx.x == 0)
        out[0] = (sm[0] + sm[1]) + (sm[2] + sm[3]);
}

// ---------------------------------------------------------------------------
extern "C" void kernel_launch(void* const* d_in, const int* in_sizes, int n_in,
                              void* d_out, int out_size, void* d_ws, size_t ws_size,
                              hipStream_t stream)
{
    const float* data    = (const float*)d_in[0];
    const float* weights = (const float*)d_in[1];
    const float* means   = (const float*)d_in[2];
    const float* cov     = (const float*)d_in[3];

    const int N = in_sizes[0] / NF;

    char* ws = (char*)d_ws;
    __hip_bfloat16* g   = (__hip_bfloat16*)ws;                  // 131072 B (swizzled)
    float* t            = (float*)(ws + 131072);                // 4096 B
    float* Cc           = (float*)(ws + 131072 + 4096);         // 64 B
    unsigned int* flag  = (unsigned int*)(ws + 131072 + 4096 + 64);   // 64 B
    float* partials     = (float*)(ws + 131072 + 4096 + 64 + 64);     // totalWaves*4

    const int nTiles     = (N + TPW * 16 - 1) / (TPW * 16);
    const int totalWaves = MAIN_BLOCKS * MAIN_WAVES;

    hipMemsetAsync(flag, 0, sizeof(unsigned int), stream);   // deterministic per call

    gmm_fused<<<MAIN_BLOCKS, 64 * MAIN_WAVES, 0, stream>>>(
        cov, means, weights, data, g, t, Cc, flag, partials, nTiles, N, totalWaves);
    gmm_reduce<<<1, 256, 0, stream>>>(partials, totalWaves, (float*)d_out);
}

// Round 18
// 112.135 us; speedup vs baseline: 1.0913x; 1.0913x over previous
//
#include <hip/hip_runtime.h>
#include <hip/hip_bf16.h>
#include <math.h>

#define NF 64
#define NC 16
#define MAIN_BLOCKS 256
#define MAIN_WAVES  13                 // 832 thr; 3328 waves vs 3125 tiles, all CUs
#define TPW 4                          // 16-sample subtiles per wave (64 samples)

typedef __bf16 bf16x8 __attribute__((ext_vector_type(8)));
typedef float f32x4 __attribute__((ext_vector_type(4)));
typedef unsigned int u32;

// async global->LDS, 16B/lane. LDS dest = wave-uniform base (HW adds lane*16).
__device__ __forceinline__ void stage16(const void* gsrc, void* ldst) {
    __builtin_amdgcn_global_load_lds(
        (const __attribute__((address_space(1))) u32*)gsrc,
        (__attribute__((address_space(3))) u32*)ldst,
        16, 0, 0);
}

// ---------------------------------------------------------------------------
// Kernel 1 v8 (unchanged): 4-wave cooperative Cholesky + inverse, rolled
// phase loops (L1I-resident ~13KB). See round-8 notes.
// ---------------------------------------------------------------------------
__global__ __launch_bounds__(256) void gmm_precompute(
    const float* __restrict__ cov,
    const float* __restrict__ means,
    const float* __restrict__ weights,
    __hip_bfloat16* __restrict__ g,
    float* __restrict__ t,
    float* __restrict__ Cc)
{
    const int w = threadIdx.x >> 6;   // wave 0..3: rows [16w,16w+16)
    const int c = threadIdx.x & 63;   // lane owns column c
    const int k = blockIdx.x;

    __shared__ __align__(16) float LT[NF][68];   // LT[j][r] = L[r][j]
    __shared__ float Xs[NF][65];                 // Xs[i][c] = G[i][c]
    __shared__ __align__(16) float wb2[2][68];   // ping-pong published row
    __shared__ __align__(16) float gw2[2][68];   // ping-pong published G row

    float a_loc[16];
    {
        const float* src = cov + (long)k * NF * NF + (w * 16) * NF + c;
        #pragma unroll
        for (int r = 0; r < 16; ++r)
            a_loc[r] = src[r * NF];
    }

    float rsq_loc[16];
    float logdiag = 0.0f;

    #pragma unroll 1
    for (int q = 0; q < 4; ++q) {
        #pragma unroll
        for (int jj = 0; jj < 16; ++jj) {
            float* wb = wb2[jj & 1];
            if (w == q) wb[c] = a_loc[jj];       // publish trailing row j
            __syncthreads();
            const int j = q * 16 + jj;
            float ajc = wb[c];
            float d   = wb[j];
            float sq  = sqrtf(d);
            float rsq = __builtin_amdgcn_rcpf(sq);
            float rd  = __builtin_amdgcn_rcpf(d);
            logdiag += 0.5f * __logf(d);
            if (w == q) rsq_loc[jj] = rsq;
            LT[j][c] = ajc * rsq;
            float beta = ajc * rd;
            const float4* wv = (const float4*)(wb + w * 16);
            #pragma unroll
            for (int rr = 0; rr < 16; rr += 4) {
                float4 v = wv[rr >> 2];
                a_loc[rr]     = fmaf(-v.x, beta, a_loc[rr]);
                a_loc[rr + 1] = fmaf(-v.y, beta, a_loc[rr + 1]);
                a_loc[rr + 2] = fmaf(-v.z, beta, a_loc[rr + 2]);
                a_loc[rr + 3] = fmaf(-v.w, beta, a_loc[rr + 3]);
            }
        }
    }

    float s_loc[16];
    #pragma unroll
    for (int r = 0; r < 16; ++r)
        s_loc[r] = (w * 16 + r == c) ? 1.0f : 0.0f;

    #pragma unroll 1
    for (int q = 0; q < 4; ++q) {
        #pragma unroll
        for (int ii = 0; ii < 16; ++ii) {
            const int i = q * 16 + ii;
            float* gw = gw2[ii & 1];
            if (w == q) {
                float gv = s_loc[ii] * rsq_loc[ii];
                gw[c] = gv;
                Xs[i][c] = gv;
            }
            __syncthreads();
            float gc = gw[c];
            const float4* lv4 = (const float4*)(&LT[i][w * 16]);
            #pragma unroll
            for (int rr = 0; rr < 16; rr += 4) {
                float4 v = lv4[rr >> 2];
                s_loc[rr]     = fmaf(-v.x, gc, s_loc[rr]);
                s_loc[rr + 1] = fmaf(-v.y, gc, s_loc[rr + 1]);
                s_loc[rr + 2] = fmaf(-v.z, gc, s_loc[rr + 2]);
                s_loc[rr + 3] = fmaf(-v.w, gc, s_loc[rr + 3]);
            }
        }
    }
    __syncthreads();

    // g row c: chunks jb=2w,2w+1, XOR-swizzled (jb ^ (row&7))
    {
        __hip_bfloat16* grow = g + ((long)(k * NF + c)) * NF;
        #pragma unroll
        for (int h = 0; h < 2; ++h) {
            int jb = w * 2 + h;
            bf16x8 v;
            #pragma unroll
            for (int u = 0; u < 8; ++u)
                v[u] = (__bf16)Xs[c][jb * 8 + u];
            *(bf16x8*)(grow + ((jb ^ (c & 7)) * 8)) = v;
        }
    }

    if (w == 0) {
        const float* mu = means + k * NF;
        float a0 = 0.0f, a1 = 0.0f;
        #pragma unroll
        for (int j = 0; j < NF; j += 2) {
            a0 = fmaf(Xs[c][j],     mu[j],     a0);
            a1 = fmaf(Xs[c][j + 1], mu[j + 1], a1);
        }
        t[k * NF + c] = a0 + a1;
        if (c == 0)
            Cc[k] = __logf(weights[k]) - 0.5f * (float)NF * 1.8378770664093453f - logdiag;
    }
}

// ---------------------------------------------------------------------------
// Kernel 2 v18: v16 body (best measured) + LAST-BLOCK final reduction:
// every block writes its 13 partials, release-fences, bumps a device
// counter ONCE (no spinning -- unlike v17's failed flag-wait); the block
// that observes count==255 acquire-fences and reduces all 3328 partials
// in FIXED order (bit-deterministic regardless of which block is last).
// Deletes the gmm_reduce launch + inter-kernel gap.
// ---------------------------------------------------------------------------
__global__ __launch_bounds__(832) void gmm_main(
    const float* __restrict__ data,
    const char* __restrict__ gsw,         // swizzled bf16 G, [NC][8192 B]
    const float* __restrict__ t,
    const float* __restrict__ Cc,
    float* __restrict__ partials,
    unsigned int* __restrict__ done,      // pre-zeroed per call
    float* __restrict__ out,
    int nTiles, int N, int totalWaves)
{
    __shared__ __align__(16) char gbuf[NC * 8192];   // 128 KiB
    __shared__ __align__(16) float nt_lds[NC * NF];  // negated t
    __shared__ float cc_lds[NC];
    __shared__ float sm2[MAIN_WAVES];
    __shared__ unsigned int lastFlag;

    const int tidx = threadIdx.x;
    const int w    = tidx >> 6;
    const int lane = tidx & 63;
    const int l15  = lane & 15;
    const int lg   = lane >> 4;

    // stage G: wave w covers comps {w, w+13} (<16)
    for (int i = w; i < NC; i += MAIN_WAVES) {
        const char* src = gsw + (size_t)i * 8192;
        char* dst = gbuf + (size_t)i * 8192;
        #pragma unroll
        for (int u = 0; u < 8; ++u)
            stage16(src + u * 1024 + lane * 16, dst + u * 1024);
    }

    for (int i = tidx; i < NC * NF; i += 64 * MAIN_WAVES) nt_lds[i] = -t[i];
    if (tidx < NC) cc_lds[tidx] = Cc[tidx];

    const int gid = blockIdx.x * MAIN_WAVES + w;

    // swizzled LDS byte offsets (static per lane)
    int offA[4], offB[4];
    #pragma unroll
    for (int rc = 0; rc < 4; ++rc) {
        int row = rc * 16 + l15;
        offA[rc] = row * 128 + ((lg       ^ (l15 & 7)) * 16);
        offB[rc] = row * 128 + (((lg + 4) ^ (l15 & 7)) * 16);
    }

    // first tile's x fragments (overlaps the staging flight)
    bf16x8 xf[TPW][2];
    if (gid < nTiles) {
        const long base = (long)gid * (TPW * 16);
        #pragma unroll
        for (int st = 0; st < TPW; ++st) {
            long row = base + st * 16 + l15;
            if (row > (long)N - 1) row = (long)N - 1;
            const float* xp = data + row * NF + lg * 8;
            float4 a0 = *(const float4*)(xp);
            float4 a1 = *(const float4*)(xp + 4);
            float4 b0 = *(const float4*)(xp + 32);
            float4 b1 = *(const float4*)(xp + 36);
            bf16x8 f0, f1;
            f0[0] = (__bf16)a0.x; f0[1] = (__bf16)a0.y;
            f0[2] = (__bf16)a0.z; f0[3] = (__bf16)a0.w;
            f0[4] = (__bf16)a1.x; f0[5] = (__bf16)a1.y;
            f0[6] = (__bf16)a1.z; f0[7] = (__bf16)a1.w;
            f1[0] = (__bf16)b0.x; f1[1] = (__bf16)b0.y;
            f1[2] = (__bf16)b0.z; f1[3] = (__bf16)b0.w;
            f1[4] = (__bf16)b1.x; f1[5] = (__bf16)b1.y;
            f1[6] = (__bf16)b1.z; f1[7] = (__bf16)b1.w;
            xf[st][0] = f0;
            xf[st][1] = f1;
        }
    }

    __syncthreads();   // G + t staged

    float wavePartial = 0.0f;

    #pragma unroll 1
    for (int tile = gid; tile < nTiles; tile += totalWaves) {
        const long base = (long)tile * (TPW * 16);
        if (tile != gid) {     // grid-stride continuation (cold path)
            #pragma unroll
            for (int st = 0; st < TPW; ++st) {
                long row = base + st * 16 + l15;
                if (row > (long)N - 1) row = (long)N - 1;
                const float* xp = data + row * NF + lg * 8;
                float4 a0 = *(const float4*)(xp);
                float4 a1 = *(const float4*)(xp + 4);
                float4 b0 = *(const float4*)(xp + 32);
                float4 b1 = *(const float4*)(xp + 36);
                bf16x8 f0, f1;
                f0[0] = (__bf16)a0.x; f0[1] = (__bf16)a0.y;
                f0[2] = (__bf16)a0.z; f0[3] = (__bf16)a0.w;
                f0[4] = (__bf16)a1.x; f0[5] = (__bf16)a1.y;
                f0[6] = (__bf16)a1.z; f0[7] = (__bf16)a1.w;
                f1[0] = (__bf16)b0.x; f1[1] = (__bf16)b0.y;
                f1[2] = (__bf16)b0.z; f1[3] = (__bf16)b0.w;
                f1[4] = (__bf16)b1.x; f1[5] = (__bf16)b1.y;
                f1[6] = (__bf16)b1.z; f1[7] = (__bf16)b1.w;
                xf[st][0] = f0;
                xf[st][1] = f1;
            }
        }

        float m[TPW], s[TPW];
        #pragma unroll
        for (int st = 0; st < TPW; ++st) { m[st] = -INFINITY; s[st] = 0.0f; }

        #pragma unroll 2
        for (int ii = 0; ii < NC; ++ii) {
            const int kk = (ii + w) & (NC - 1);      // per-wave stagger
            float mah[TPW];
            #pragma unroll
            for (int st = 0; st < TPW; ++st) mah[st] = 0.0f;

            const char* gk = gbuf + kk * 8192;
            const float* ntk = &nt_lds[kk * NF];

            // rc 0,1: rows 0..31 of lower-tri G -> cols 32..63 are ZERO
            #pragma unroll
            for (int rc = 0; rc < 2; ++rc) {
                bf16x8 ga = *(const bf16x8*)(gk + offA[rc]);
                f32x4 ntv = *(const f32x4*)(ntk + rc * 16 + lg * 4);
                #pragma unroll
                for (int st = 0; st < TPW; ++st) {
                    f32x4 acc = ntv;
                    acc = __builtin_amdgcn_mfma_f32_16x16x32_bf16(ga, xf[st][0], acc, 0, 0, 0);
                    mah[st] = fmaf(acc[0], acc[0], mah[st]);
                    mah[st] = fmaf(acc[1], acc[1], mah[st]);
                    mah[st] = fmaf(acc[2], acc[2], mah[st]);
                    mah[st] = fmaf(acc[3], acc[3], mah[st]);
                }
            }
            // rc 2,3: full rows
            #pragma unroll
            for (int rc = 2; rc < 4; ++rc) {
                bf16x8 ga = *(const bf16x8*)(gk + offA[rc]);
                bf16x8 gb = *(const bf16x8*)(gk + offB[rc]);
                f32x4 ntv = *(const f32x4*)(ntk + rc * 16 + lg * 4);
                #pragma unroll
                for (int st = 0; st < TPW; ++st) {
                    f32x4 acc = ntv;
                    acc = __builtin_amdgcn_mfma_f32_16x16x32_bf16(ga, xf[st][0], acc, 0, 0, 0);
                    acc = __builtin_amdgcn_mfma_f32_16x16x32_bf16(gb, xf[st][1], acc, 0, 0, 0);
                    mah[st] = fmaf(acc[0], acc[0], mah[st]);
                    mah[st] = fmaf(acc[1], acc[1], mah[st]);
                    mah[st] = fmaf(acc[2], acc[2], mah[st]);
                    mah[st] = fmaf(acc[3], acc[3], mah[st]);
                }
            }

            // defer-max logsumexp
            float Ck = cc_lds[kk];
            float wlp[TPW];
            float dmax = -INFINITY;
            #pragma unroll
            for (int st = 0; st < TPW; ++st) {
                float v = mah[st];
                v += __shfl_xor(v, 16);
                v += __shfl_xor(v, 32);          // all lanes hold full maha
                wlp[st] = fmaf(-0.5f, v, Ck);
                dmax = fmaxf(dmax, wlp[st] - m[st]);
            }
            if (__any(dmax > 60.0f)) {           // rare after first comp
                #pragma unroll
                for (int st = 0; st < TPW; ++st) {
                    float mn = fmaxf(m[st], wlp[st]);
                    s[st] = s[st] * __expf(m[st] - mn) + __expf(wlp[st] - mn);
                    m[st] = mn;
                }
            } else {                             // common: 1 exp + 1 add
                #pragma unroll
                for (int st = 0; st < TPW; ++st)
                    s[st] += __expf(wlp[st] - m[st]);
            }
        }

        if (lg == 0) {
            #pragma unroll
            for (int st = 0; st < TPW; ++st) {
                long sid = base + st * 16 + l15;
                if (sid < (long)N)
                    wavePartial += m[st] + __logf(s[st]);
            }
        }
    }

    #pragma unroll
    for (int off = 1; off < 64; off <<= 1)
        wavePartial += __shfl_xor(wavePartial, off);
    if (lane == 0)
        partials[gid] = wavePartial;

    // ---- last-block deterministic final reduction (no spinning) ----
    __threadfence();                     // release: partials visible device-wide
    __syncthreads();                     // all waves of this block have fenced
    if (tidx == 0)
        lastFlag = (atomicAdd(done, 1u) == MAIN_BLOCKS - 1) ? 1u : 0u;
    __syncthreads();
    if (lastFlag) {
        __threadfence();                 // acquire: invalidate stale lines
        float s = 0.0f;
        for (int i = tidx; i < totalWaves; i += 64 * MAIN_WAVES)
            s += partials[i];            // fixed per-thread order
        #pragma unroll
        for (int off = 1; off < 64; off <<= 1)
            s += __shfl_xor(s, off);
        if (lane == 0) sm2[w] = s;
        __syncthreads();
        if (tidx == 0) {
            float r = 0.0f;
            #pragma unroll
            for (int i = 0; i < MAIN_WAVES; ++i) r += sm2[i];   // fixed order
            out[0] = r;
        }
    }
}

// ---------------------------------------------------------------------------
extern "C" void kernel_launch(void* const* d_in, const int* in_sizes, int n_in,
                              void* d_out, int out_size, void* d_ws, size_t ws_size,
                              hipStream_t stream)
{
    const float* data    = (const float*)d_in[0];
    const float* weights = (const float*)d_in[1];
    const float* means   = (const float*)d_in[2];
    const float* cov     = (const float*)d_in[3];

    const int N = in_sizes[0] / NF;

    char* ws = (char*)d_ws;
    __hip_bfloat16* g  = (__hip_bfloat16*)ws;                   // 131072 B (swizzled)
    float* t           = (float*)(ws + 131072);                 // 4096 B
    float* Cc          = (float*)(ws + 131072 + 4096);          // 64 B
    unsigned int* done = (unsigned int*)(ws + 131072 + 4096 + 64);  // 64 B
    float* partials    = (float*)(ws + 131072 + 4096 + 64 + 64);    // totalWaves*4

    const int nTiles     = (N + TPW * 16 - 1) / (TPW * 16);
    const int totalWaves = MAIN_BLOCKS * MAIN_WAVES;

    hipMemsetAsync(done, 0, sizeof(unsigned int), stream);   // per-call reset

    gmm_precompute<<<NC, 256, 0, stream>>>(cov, means, weights, g, t, Cc);
    gmm_main<<<MAIN_BLOCKS, 64 * MAIN_WAVES, 0, stream>>>(
        data, (const char*)g, t, Cc, partials, done, (float*)d_out,
        nTiles, N, totalWaves);
}

// Round 19
// 63.770 us; speedup vs baseline: 1.9189x; 1.7584x over previous
//
#include <hip/hip_runtime.h>
#include <hip/hip_bf16.h>
#include <math.h>

#define NF 64
#define NC 16
#define MAIN_BLOCKS 256
#define MAIN_WAVES  13                 // 832 thr; 3328 waves vs 3125 tiles, all CUs
#define TPW 4                          // 16-sample subtiles per wave (64 samples)

typedef __bf16 bf16x8 __attribute__((ext_vector_type(8)));
typedef float f32x4 __attribute__((ext_vector_type(4)));
typedef unsigned int u32;

// async global->LDS, 16B/lane. LDS dest = wave-uniform base (HW adds lane*16).
__device__ __forceinline__ void stage16(const void* gsrc, void* ldst) {
    __builtin_amdgcn_global_load_lds(
        (const __attribute__((address_space(1))) u32*)gsrc,
        (__attribute__((address_space(3))) u32*)ldst,
        16, 0, 0);
}

// ---------------------------------------------------------------------------
// Kernel 1 v19: FUSED Cholesky + inverse, one 64-round pipeline (was 128).
// 16 blocks x 256 threads (4 waves). Lane (w,c): rows [16w,16w+16) of
// column c in registers (a_loc = trailing A, s_loc = S with S0=I).
// Round j (one barrier each):
//   publish A-row j (owner wave j>>4)  and  G-row j-1 (owner (j-1)>>4,
//   gv = s_loc[(j-1)&15] * rsq_prev -- rsq from round j-1, wave-uniform)
//   barrier
//   Cholesky update for step j (writes LT[j]) + sub update for step j-1
//   (reads LT[j-1], written last round).
// Safety: wb/gw ping-pong buffers are overwritten 2 rounds after their read,
// separated by a barrier; junk updates to published s_loc rows are never
// re-read (same invariant as v8). Epilogue publishes G row 63.
// Outputs unchanged: swizzled g (jb ^ (row&7)), t, Cc.
// ---------------------------------------------------------------------------
__global__ __launch_bounds__(256) void gmm_precompute(
    const float* __restrict__ cov,
    const float* __restrict__ means,
    const float* __restrict__ weights,
    __hip_bfloat16* __restrict__ g,
    float* __restrict__ t,
    float* __restrict__ Cc)
{
    const int w = threadIdx.x >> 6;   // wave 0..3: rows [16w,16w+16)
    const int c = threadIdx.x & 63;   // lane owns column c
    const int k = blockIdx.x;

    __shared__ __align__(16) float LT[NF][68];   // LT[j][r] = L[r][j]
    __shared__ float Xs[NF][65];                 // Xs[i][c] = G[i][c]
    __shared__ __align__(16) float wb2[2][68];   // ping-pong published A row
    __shared__ __align__(16) float gw2[2][68];   // ping-pong published G row

    float a_loc[16];
    {
        const float* src = cov + (long)k * NF * NF + (w * 16) * NF + c;
        #pragma unroll
        for (int r = 0; r < 16; ++r)
            a_loc[r] = src[r * NF];
    }

    float s_loc[16];
    #pragma unroll
    for (int r = 0; r < 16; ++r)
        s_loc[r] = (w * 16 + r == c) ? 1.0f : 0.0f;

    float logdiag  = 0.0f;
    float rsq_prev = 0.0f;            // rsq of the previous step (uniform)

    #pragma unroll 1
    for (int q = 0; q < 4; ++q) {
        #pragma unroll
        for (int jj = 0; jj < 16; ++jj) {
            const int j = q * 16 + jj;
            float* wb = wb2[jj & 1];            // j&1 == jj&1 (q*16 even)
            float* gw = gw2[jj & 1];

            if (w == q) wb[c] = a_loc[jj];      // publish A-row j
            if (j > 0) {                        // publish G-row j-1
                const int pw = (jj == 0) ? (q - 1) : q;       // owner wave
                const int pi = (jj == 0) ? 15 : (jj - 1);     // static index
                if (w == pw) {
                    float gv = s_loc[pi] * rsq_prev;
                    gw[c] = gv;
                    Xs[j - 1][c] = gv;
                }
            }
            __syncthreads();

            // ---- Cholesky step j ----
            float ajc = wb[c];
            float d   = wb[j];
            float sq  = sqrtf(d);
            float rsq = __builtin_amdgcn_rcpf(sq);
            float rd  = __builtin_amdgcn_rcpf(d);
            logdiag += 0.5f * __logf(d);
            rsq_prev = rsq;
            LT[j][c] = ajc * rsq;               // column j of L (own slot)
            float beta = ajc * rd;
            const float4* wv = (const float4*)(wb + w * 16);
            #pragma unroll
            for (int rr = 0; rr < 16; rr += 4) {
                float4 v = wv[rr >> 2];
                a_loc[rr]     = fmaf(-v.x, beta, a_loc[rr]);
                a_loc[rr + 1] = fmaf(-v.y, beta, a_loc[rr + 1]);
                a_loc[rr + 2] = fmaf(-v.z, beta, a_loc[rr + 2]);
                a_loc[rr + 3] = fmaf(-v.w, beta, a_loc[rr + 3]);
            }

            // ---- substitution step j-1 ----
            if (j > 0) {
                float gc = gw[c];
                const float4* lv4 = (const float4*)(&LT[j - 1][w * 16]);
                #pragma unroll
                for (int rr = 0; rr < 16; rr += 4) {
                    float4 v = lv4[rr >> 2];
                    s_loc[rr]     = fmaf(-v.x, gc, s_loc[rr]);
                    s_loc[rr + 1] = fmaf(-v.y, gc, s_loc[rr + 1]);
                    s_loc[rr + 2] = fmaf(-v.z, gc, s_loc[rr + 2]);
                    s_loc[rr + 3] = fmaf(-v.w, gc, s_loc[rr + 3]);
                }
            }
        }
    }

    // epilogue: G row 63 (owner wave 3)
    if (w == 3) Xs[63][c] = s_loc[15] * rsq_prev;
    __syncthreads();

    // g row c: chunks jb=2w,2w+1, XOR-swizzled (jb ^ (row&7))
    {
        __hip_bfloat16* grow = g + ((long)(k * NF + c)) * NF;
        #pragma unroll
        for (int h = 0; h < 2; ++h) {
            int jb = w * 2 + h;
            bf16x8 v;
            #pragma unroll
            for (int u = 0; u < 8; ++u)
                v[u] = (__bf16)Xs[c][jb * 8 + u];
            *(bf16x8*)(grow + ((jb ^ (c & 7)) * 8)) = v;
        }
    }

    if (w == 0) {
        const float* mu = means + k * NF;
        float a0 = 0.0f, a1 = 0.0f;
        #pragma unroll
        for (int j = 0; j < NF; j += 2) {
            a0 = fmaf(Xs[c][j],     mu[j],     a0);
            a1 = fmaf(Xs[c][j + 1], mu[j + 1], a1);
        }
        t[k * NF + c] = a0 + a1;
        if (c == 0)
            Cc[k] = __logf(weights[k]) - 0.5f * (float)NF * 1.8378770664093453f - logdiag;
    }
}

// ---------------------------------------------------------------------------
// Kernel 2 v16 (unchanged, best measured): 16 comps/block, 13 waves,
// 0-conflict swizzle, triangular skip, stagger, one barrier, defer-max LSE.
// ---------------------------------------------------------------------------
__global__ __launch_bounds__(832) void gmm_main(
    const float* __restrict__ data,
    const char* __restrict__ gsw,         // swizzled bf16 G, [NC][8192 B]
    const float* __restrict__ t,
    const float* __restrict__ Cc,
    float* __restrict__ partials,
    int nTiles, int N, int totalWaves)
{
    __shared__ __align__(16) char gbuf[NC * 8192];   // 128 KiB
    __shared__ __align__(16) float nt_lds[NC * NF];  // negated t
    __shared__ float cc_lds[NC];

    const int tidx = threadIdx.x;
    const int w    = tidx >> 6;
    const int lane = tidx & 63;
    const int l15  = lane & 15;
    const int lg   = lane >> 4;

    // stage G: wave w covers comps {w, w+13} (<16)
    for (int i = w; i < NC; i += MAIN_WAVES) {
        const char* src = gsw + (size_t)i * 8192;
        char* dst = gbuf + (size_t)i * 8192;
        #pragma unroll
        for (int u = 0; u < 8; ++u)
            stage16(src + u * 1024 + lane * 16, dst + u * 1024);
    }

    for (int i = tidx; i < NC * NF; i += 64 * MAIN_WAVES) nt_lds[i] = -t[i];
    if (tidx < NC) cc_lds[tidx] = Cc[tidx];

    const int gid = blockIdx.x * MAIN_WAVES + w;

    // swizzled LDS byte offsets (static per lane)
    int offA[4], offB[4];
    #pragma unroll
    for (int rc = 0; rc < 4; ++rc) {
        int row = rc * 16 + l15;
        offA[rc] = row * 128 + ((lg       ^ (l15 & 7)) * 16);
        offB[rc] = row * 128 + (((lg + 4) ^ (l15 & 7)) * 16);
    }

    // first tile's x fragments (overlaps the staging flight)
    bf16x8 xf[TPW][2];
    if (gid < nTiles) {
        const long base = (long)gid * (TPW * 16);
        #pragma unroll
        for (int st = 0; st < TPW; ++st) {
            long row = base + st * 16 + l15;
            if (row > (long)N - 1) row = (long)N - 1;
            const float* xp = data + row * NF + lg * 8;
            float4 a0 = *(const float4*)(xp);
            float4 a1 = *(const float4*)(xp + 4);
            float4 b0 = *(const float4*)(xp + 32);
            float4 b1 = *(const float4*)(xp + 36);
            bf16x8 f0, f1;
            f0[0] = (__bf16)a0.x; f0[1] = (__bf16)a0.y;
            f0[2] = (__bf16)a0.z; f0[3] = (__bf16)a0.w;
            f0[4] = (__bf16)a1.x; f0[5] = (__bf16)a1.y;
            f0[6] = (__bf16)a1.z; f0[7] = (__bf16)a1.w;
            f1[0] = (__bf16)b0.x; f1[1] = (__bf16)b0.y;
            f1[2] = (__bf16)b0.z; f1[3] = (__bf16)b0.w;
            f1[4] = (__bf16)b1.x; f1[5] = (__bf16)b1.y;
            f1[6] = (__bf16)b1.z; f1[7] = (__bf16)b1.w;
            xf[st][0] = f0;
            xf[st][1] = f1;
        }
    }

    __syncthreads();   // G + t staged; only barrier in the kernel

    float wavePartial = 0.0f;

    #pragma unroll 1
    for (int tile = gid; tile < nTiles; tile += totalWaves) {
        const long base = (long)tile * (TPW * 16);
        if (tile != gid) {     // grid-stride continuation (cold path)
            #pragma unroll
            for (int st = 0; st < TPW; ++st) {
                long row = base + st * 16 + l15;
                if (row > (long)N - 1) row = (long)N - 1;
                const float* xp = data + row * NF + lg * 8;
                float4 a0 = *(const float4*)(xp);
                float4 a1 = *(const float4*)(xp + 4);
                float4 b0 = *(const float4*)(xp + 32);
                float4 b1 = *(const float4*)(xp + 36);
                bf16x8 f0, f1;
                f0[0] = (__bf16)a0.x; f0[1] = (__bf16)a0.y;
                f0[2] = (__bf16)a0.z; f0[3] = (__bf16)a0.w;
                f0[4] = (__bf16)a1.x; f0[5] = (__bf16)a1.y;
                f0[6] = (__bf16)a1.z; f0[7] = (__bf16)a1.w;
                f1[0] = (__bf16)b0.x; f1[1] = (__bf16)b0.y;
                f1[2] = (__bf16)b0.z; f1[3] = (__bf16)b0.w;
                f1[4] = (__bf16)b1.x; f1[5] = (__bf16)b1.y;
                f1[6] = (__bf16)b1.z; f1[7] = (__bf16)b1.w;
                xf[st][0] = f0;
                xf[st][1] = f1;
            }
        }

        float m[TPW], s[TPW];
        #pragma unroll
        for (int st = 0; st < TPW; ++st) { m[st] = -INFINITY; s[st] = 0.0f; }

        #pragma unroll 2
        for (int ii = 0; ii < NC; ++ii) {
            const int kk = (ii + w) & (NC - 1);      // per-wave stagger
            float mah[TPW];
            #pragma unroll
            for (int st = 0; st < TPW; ++st) mah[st] = 0.0f;

            const char* gk = gbuf + kk * 8192;
            const float* ntk = &nt_lds[kk * NF];

            // rc 0,1: rows 0..31 of lower-tri G -> cols 32..63 are ZERO
            #pragma unroll
            for (int rc = 0; rc < 2; ++rc) {
                bf16x8 ga = *(const bf16x8*)(gk + offA[rc]);
                f32x4 ntv = *(const f32x4*)(ntk + rc * 16 + lg * 4);
                #pragma unroll
                for (int st = 0; st < TPW; ++st) {
                    f32x4 acc = ntv;
                    acc = __builtin_amdgcn_mfma_f32_16x16x32_bf16(ga, xf[st][0], acc, 0, 0, 0);
                    mah[st] = fmaf(acc[0], acc[0], mah[st]);
                    mah[st] = fmaf(acc[1], acc[1], mah[st]);
                    mah[st] = fmaf(acc[2], acc[2], mah[st]);
                    mah[st] = fmaf(acc[3], acc[3], mah[st]);
                }
            }
            // rc 2,3: full rows
            #pragma unroll
            for (int rc = 2; rc < 4; ++rc) {
                bf16x8 ga = *(const bf16x8*)(gk + offA[rc]);
                bf16x8 gb = *(const bf16x8*)(gk + offB[rc]);
                f32x4 ntv = *(const f32x4*)(ntk + rc * 16 + lg * 4);
                #pragma unroll
                for (int st = 0; st < TPW; ++st) {
                    f32x4 acc = ntv;
                    acc = __builtin_amdgcn_mfma_f32_16x16x32_bf16(ga, xf[st][0], acc, 0, 0, 0);
                    acc = __builtin_amdgcn_mfma_f32_16x16x32_bf16(gb, xf[st][1], acc, 0, 0, 0);
                    mah[st] = fmaf(acc[0], acc[0], mah[st]);
                    mah[st] = fmaf(acc[1], acc[1], mah[st]);
                    mah[st] = fmaf(acc[2], acc[2], mah[st]);
                    mah[st] = fmaf(acc[3], acc[3], mah[st]);
                }
            }

            // defer-max logsumexp
            float Ck = cc_lds[kk];
            float wlp[TPW];
            float dmax = -INFINITY;
            #pragma unroll
            for (int st = 0; st < TPW; ++st) {
                float v = mah[st];
                v += __shfl_xor(v, 16);
                v += __shfl_xor(v, 32);          // all lanes hold full maha
                wlp[st] = fmaf(-0.5f, v, Ck);
                dmax = fmaxf(dmax, wlp[st] - m[st]);
            }
            if (__any(dmax > 60.0f)) {           // rare after first comp
                #pragma unroll
                for (int st = 0; st < TPW; ++st) {
                    float mn = fmaxf(m[st], wlp[st]);
                    s[st] = s[st] * __expf(m[st] - mn) + __expf(wlp[st] - mn);
                    m[st] = mn;
                }
            } else {                             // common: 1 exp + 1 add
                #pragma unroll
                for (int st = 0; st < TPW; ++st)
                    s[st] += __expf(wlp[st] - m[st]);
            }
        }

        if (lg == 0) {
            #pragma unroll
            for (int st = 0; st < TPW; ++st) {
                long sid = base + st * 16 + l15;
                if (sid < (long)N)
                    wavePartial += m[st] + __logf(s[st]);
            }
        }
    }

    #pragma unroll
    for (int off = 1; off < 64; off <<= 1)
        wavePartial += __shfl_xor(wavePartial, off);
    if (lane == 0)
        partials[gid] = wavePartial;
}

// ---------------------------------------------------------------------------
// Kernel 3: deterministic final reduction over per-wave partials.
// ---------------------------------------------------------------------------
__global__ __launch_bounds__(256) void gmm_reduce(
    const float* __restrict__ partials, int n, float* __restrict__ out)
{
    float s = 0.0f;
    for (int i = threadIdx.x; i < n; i += 256)
        s += partials[i];
    #pragma unroll
    for (int off = 1; off < 64; off <<= 1)
        s += __shfl_xor(s, off);
    __shared__ float sm[4];
    const int wave = threadIdx.x >> 6;
    const int lane = threadIdx.x & 63;
    if (lane == 0) sm[wave] = s;
    __syncthreads();
    if (threadIdx.x == 0)
        out[0] = (sm[0] + sm[1]) + (sm[2] + sm[3]);
}

// ---------------------------------------------------------------------------
extern "C" void kernel_launch(void* const* d_in, const int* in_sizes, int n_in,
                              void* d_out, int out_size, void* d_ws, size_t ws_size,
                              hipStream_t stream)
{
    const float* data    = (const float*)d_in[0];
    const float* weights = (const float*)d_in[1];
    const float* means   = (const float*)d_in[2];
    const float* cov     = (const float*)d_in[3];

    const int N = in_sizes[0] / NF;

    char* ws = (char*)d_ws;
    __hip_bfloat16* g = (__hip_bfloat16*)ws;                    // 131072 B (swizzled)
    float* t          = (float*)(ws + 131072);                  // 4096 B
    float* Cc         = (float*)(ws + 131072 + 4096);           // 64 B
    float* partials   = (float*)(ws + 131072 + 4096 + 64);      // totalWaves * 4 B

    const int nTiles     = (N + TPW * 16 - 1) / (TPW * 16);
    const int totalWaves = MAIN_BLOCKS * MAIN_WAVES;

    gmm_precompute<<<NC, 256, 0, stream>>>(cov, means, weights, g, t, Cc);
    gmm_main<<<MAIN_BLOCKS, 64 * MAIN_WAVES, 0, stream>>>(
        data, (const char*)g, t, Cc, partials, nTiles, N, totalWaves);
    gmm_reduce<<<1, 256, 0, stream>>>(partials, totalWaves, (float*)d_out);
}

// Round 20
// 62.239 us; speedup vs baseline: 1.9662x; 1.0246x over previous
//
#include <hip/hip_runtime.h>
#include <hip/hip_bf16.h>
#include <math.h>

#define NF 64
#define NC 16
#define MAIN_BLOCKS 256
#define MAIN_WAVES  13                 // 832 thr; 3328 waves vs 3125 tiles, all CUs
#define TPW 4                          // 16-sample subtiles per wave (64 samples)

typedef __bf16 bf16x8 __attribute__((ext_vector_type(8)));
typedef float f32x4 __attribute__((ext_vector_type(4)));
typedef unsigned int u32;

// async global->LDS, 16B/lane. LDS dest = wave-uniform base (HW adds lane*16).
__device__ __forceinline__ void stage16(const void* gsrc, void* ldst) {
    __builtin_amdgcn_global_load_lds(
        (const __attribute__((address_space(1))) u32*)gsrc,
        (__attribute__((address_space(3))) u32*)ldst,
        16, 0, 0);
}

// ---------------------------------------------------------------------------
// Kernel 1 v20: RANK-2 fused Cholesky + inverse: 32 rounds, 33 barriers
// (v19 was 64 rounds / 65 barriers; v8 was 128).
// 16 blocks x 256 threads. Lane (w,c): rows [16w,16w+16) of column c in regs.
// Round r (j = 2r; j and j+1 always in the same owner wave since j even):
//   publish A-rows j, j+1 (pre-update) and G-rows j-2, j-1 (named regs
//   gvA/gvB computed at the end of round r-1 by their owner wave); barrier;
//   - Cholesky steps j, j+1: row j+1 corrected locally via broadcast
//     k0 = A[j+1]*rd0 (w1c = B[c]-A[c]*k0), exact rank-2 a_loc update.
//   - substitution steps j-2, j-1: rank-2 s_loc update from LT rows
//     (written last round; barrier-separated).
//   - owner wave computes G[j], G[j+1]: gvA = s_loc*rsq0, and gvB applies
//     step j's correction manually (l10 = A[j+1]*rsq0, uniform). The next
//     round re-applies step j to the then-DEAD s_loc row -- harmless
//     (same junk-on-dead-row invariant as v8/v19).
// Epilogue: Xs rows 62,63 from the final gvA/gvB. Outputs unchanged:
// swizzled g (jb ^ (row&7)), t, Cc.
// ---------------------------------------------------------------------------
__global__ __launch_bounds__(256) void gmm_precompute(
    const float* __restrict__ cov,
    const float* __restrict__ means,
    const float* __restrict__ weights,
    __hip_bfloat16* __restrict__ g,
    float* __restrict__ t,
    float* __restrict__ Cc)
{
    const int w = threadIdx.x >> 6;   // wave 0..3: rows [16w,16w+16)
    const int c = threadIdx.x & 63;   // lane owns column c
    const int k = blockIdx.x;

    __shared__ __align__(16) float LT[NF][68];   // LT[j][r] = L[r][j]
    __shared__ float Xs[NF][65];                 // Xs[i][c] = G[i][c]
    __shared__ __align__(16) float wbA2[2][68];  // ping-pong published A row j
    __shared__ __align__(16) float wbB2[2][68];  // ping-pong published A row j+1
    __shared__ __align__(16) float gwA2[2][68];  // ping-pong published G row j-2
    __shared__ __align__(16) float gwB2[2][68];  // ping-pong published G row j-1

    float a_loc[16];
    {
        const float* src = cov + (long)k * NF * NF + (w * 16) * NF + c;
        #pragma unroll
        for (int r = 0; r < 16; ++r)
            a_loc[r] = src[r * NF];
    }

    float s_loc[16];
    #pragma unroll
    for (int r = 0; r < 16; ++r)
        s_loc[r] = (w * 16 + r == c) ? 1.0f : 0.0f;

    float logdiag = 0.0f;
    float gvA = 0.0f, gvB = 0.0f;     // owner wave's pending G rows

    #pragma unroll 1
    for (int q = 0; q < 4; ++q) {
        #pragma unroll
        for (int h = 0; h < 8; ++h) {          // round r = q*8+h; steps j, j+1
            const int j = q * 16 + 2 * h;
            float* wbA = wbA2[h & 1];
            float* wbB = wbB2[h & 1];
            float* gwA = gwA2[h & 1];
            float* gwB = gwB2[h & 1];

            if (w == q) {                       // publish A rows j, j+1 (static idx)
                wbA[c] = a_loc[2 * h];
                wbB[c] = a_loc[2 * h + 1];
            }
            if (j > 0) {                        // publish G rows j-2, j-1
                const int pw = (h == 0) ? (q - 1) : q;
                if (w == pw) {
                    gwA[c] = gvA;  Xs[j - 2][c] = gvA;
                    gwB[c] = gvB;  Xs[j - 1][c] = gvB;
                }
            }
            __syncthreads();

            // ---- Cholesky steps j, j+1 ----
            float ajc = wbA[c];
            float bjc = wbB[c];
            float d0  = wbA[j];                 // pivot j (broadcast)
            float a1j = wbA[j + 1];
            float b1j = wbB[j + 1];
            float rd0 = __builtin_amdgcn_rcpf(d0);
            float k0  = a1j * rd0;              // uniform
            float d1  = fmaf(-a1j, k0, b1j);    // pivot j+1 after step j
            float rd1 = __builtin_amdgcn_rcpf(d1);
            float rsq0 = __builtin_amdgcn_rcpf(sqrtf(d0));
            float rsq1 = __builtin_amdgcn_rcpf(sqrtf(d1));
            logdiag += 0.5f * (__logf(d0) + __logf(d1));
            float w1c = fmaf(-ajc, k0, bjc);    // corrected row j+1, col c
            LT[j][c]     = ajc * rsq0;          // L columns j, j+1
            LT[j + 1][c] = w1c * rsq1;
            float beta0 = ajc * rd0;
            float beta1 = w1c * rd1;
            {
                const float4* wvA = (const float4*)(wbA + w * 16);
                const float4* wvB = (const float4*)(wbB + w * 16);
                #pragma unroll
                for (int rr = 0; rr < 16; rr += 4) {
                    float4 vA = wvA[rr >> 2];
                    float4 vB = wvB[rr >> 2];
                    float t0 = fmaf(-vA.x, k0, vB.x);   // corrected row j+1 elems
                    float t1 = fmaf(-vA.y, k0, vB.y);
                    float t2 = fmaf(-vA.z, k0, vB.z);
                    float t3 = fmaf(-vA.w, k0, vB.w);
                    a_loc[rr]     = fmaf(-t0, beta1, fmaf(-vA.x, beta0, a_loc[rr]));
                    a_loc[rr + 1] = fmaf(-t1, beta1, fmaf(-vA.y, beta0, a_loc[rr + 1]));
                    a_loc[rr + 2] = fmaf(-t2, beta1, fmaf(-vA.z, beta0, a_loc[rr + 2]));
                    a_loc[rr + 3] = fmaf(-t3, beta1, fmaf(-vA.w, beta0, a_loc[rr + 3]));
                }
            }

            // ---- substitution steps j-2, j-1 ----
            if (j > 0) {
                float gA = gwA[c];
                float gB = gwB[c];
                const float4* lvA = (const float4*)(&LT[j - 2][w * 16]);
                const float4* lvB = (const float4*)(&LT[j - 1][w * 16]);
                #pragma unroll
                for (int rr = 0; rr < 16; rr += 4) {
                    float4 vA = lvA[rr >> 2];
                    float4 vB = lvB[rr >> 2];
                    s_loc[rr]     = fmaf(-vB.x, gB, fmaf(-vA.x, gA, s_loc[rr]));
                    s_loc[rr + 1] = fmaf(-vB.y, gB, fmaf(-vA.y, gA, s_loc[rr + 1]));
                    s_loc[rr + 2] = fmaf(-vB.z, gB, fmaf(-vA.z, gA, s_loc[rr + 2]));
                    s_loc[rr + 3] = fmaf(-vB.w, gB, fmaf(-vA.w, gA, s_loc[rr + 3]));
                }
            }

            // ---- end of round: owner computes G rows j, j+1 ----
            if (w == q) {
                float l10 = a1j * rsq0;         // L[j+1][j] (uniform)
                gvA = s_loc[2 * h] * rsq0;      // s_loc complete through j-1
                gvB = fmaf(-l10, gvA, s_loc[2 * h + 1]) * rsq1;
            }
        }
    }

    // epilogue: G rows 62, 63 (owner wave 3)
    if (w == 3) { Xs[62][c] = gvA; Xs[63][c] = gvB; }
    __syncthreads();

    // g row c: chunks jb=2w,2w+1, XOR-swizzled (jb ^ (row&7))
    {
        __hip_bfloat16* grow = g + ((long)(k * NF + c)) * NF;
        #pragma unroll
        for (int h = 0; h < 2; ++h) {
            int jb = w * 2 + h;
            bf16x8 v;
            #pragma unroll
            for (int u = 0; u < 8; ++u)
                v[u] = (__bf16)Xs[c][jb * 8 + u];
            *(bf16x8*)(grow + ((jb ^ (c & 7)) * 8)) = v;
        }
    }

    if (w == 0) {
        const float* mu = means + k * NF;
        float a0 = 0.0f, a1 = 0.0f;
        #pragma unroll
        for (int j = 0; j < NF; j += 2) {
            a0 = fmaf(Xs[c][j],     mu[j],     a0);
            a1 = fmaf(Xs[c][j + 1], mu[j + 1], a1);
        }
        t[k * NF + c] = a0 + a1;
        if (c == 0)
            Cc[k] = __logf(weights[k]) - 0.5f * (float)NF * 1.8378770664093453f - logdiag;
    }
}

// ---------------------------------------------------------------------------
// Kernel 2 v16 (unchanged, best measured): 16 comps/block, 13 waves,
// 0-conflict swizzle, triangular skip, stagger, one barrier, defer-max LSE.
// ---------------------------------------------------------------------------
__global__ __launch_bounds__(832) void gmm_main(
    const float* __restrict__ data,
    const char* __restrict__ gsw,         // swizzled bf16 G, [NC][8192 B]
    const float* __restrict__ t,
    const float* __restrict__ Cc,
    float* __restrict__ partials,
    int nTiles, int N, int totalWaves)
{
    __shared__ __align__(16) char gbuf[NC * 8192];   // 128 KiB
    __shared__ __align__(16) float nt_lds[NC * NF];  // negated t
    __shared__ float cc_lds[NC];

    const int tidx = threadIdx.x;
    const int w    = tidx >> 6;
    const int lane = tidx & 63;
    const int l15  = lane & 15;
    const int lg   = lane >> 4;

    // stage G: wave w covers comps {w, w+13} (<16)
    for (int i = w; i < NC; i += MAIN_WAVES) {
        const char* src = gsw + (size_t)i * 8192;
        char* dst = gbuf + (size_t)i * 8192;
        #pragma unroll
        for (int u = 0; u < 8; ++u)
            stage16(src + u * 1024 + lane * 16, dst + u * 1024);
    }

    for (int i = tidx; i < NC * NF; i += 64 * MAIN_WAVES) nt_lds[i] = -t[i];
    if (tidx < NC) cc_lds[tidx] = Cc[tidx];

    const int gid = blockIdx.x * MAIN_WAVES + w;

    // swizzled LDS byte offsets (static per lane)
    int offA[4], offB[4];
    #pragma unroll
    for (int rc = 0; rc < 4; ++rc) {
        int row = rc * 16 + l15;
        offA[rc] = row * 128 + ((lg       ^ (l15 & 7)) * 16);
        offB[rc] = row * 128 + (((lg + 4) ^ (l15 & 7)) * 16);
    }

    // first tile's x fragments (overlaps the staging flight)
    bf16x8 xf[TPW][2];
    if (gid < nTiles) {
        const long base = (long)gid * (TPW * 16);
        #pragma unroll
        for (int st = 0; st < TPW; ++st) {
            long row = base + st * 16 + l15;
            if (row > (long)N - 1) row = (long)N - 1;
            const float* xp = data + row * NF + lg * 8;
            float4 a0 = *(const float4*)(xp);
            float4 a1 = *(const float4*)(xp + 4);
            float4 b0 = *(const float4*)(xp + 32);
            float4 b1 = *(const float4*)(xp + 36);
            bf16x8 f0, f1;
            f0[0] = (__bf16)a0.x; f0[1] = (__bf16)a0.y;
            f0[2] = (__bf16)a0.z; f0[3] = (__bf16)a0.w;
            f0[4] = (__bf16)a1.x; f0[5] = (__bf16)a1.y;
            f0[6] = (__bf16)a1.z; f0[7] = (__bf16)a1.w;
            f1[0] = (__bf16)b0.x; f1[1] = (__bf16)b0.y;
            f1[2] = (__bf16)b0.z; f1[3] = (__bf16)b0.w;
            f1[4] = (__bf16)b1.x; f1[5] = (__bf16)b1.y;
            f1[6] = (__bf16)b1.z; f1[7] = (__bf16)b1.w;
            xf[st][0] = f0;
            xf[st][1] = f1;
        }
    }

    __syncthreads();   // G + t staged; only barrier in the kernel

    float wavePartial = 0.0f;

    #pragma unroll 1
    for (int tile = gid; tile < nTiles; tile += totalWaves) {
        const long base = (long)tile * (TPW * 16);
        if (tile != gid) {     // grid-stride continuation (cold path)
            #pragma unroll
            for (int st = 0; st < TPW; ++st) {
                long row = base + st * 16 + l15;
                if (row > (long)N - 1) row = (long)N - 1;
                const float* xp = data + row * NF + lg * 8;
                float4 a0 = *(const float4*)(xp);
                float4 a1 = *(const float4*)(xp + 4);
                float4 b0 = *(const float4*)(xp + 32);
                float4 b1 = *(const float4*)(xp + 36);
                bf16x8 f0, f1;
                f0[0] = (__bf16)a0.x; f0[1] = (__bf16)a0.y;
                f0[2] = (__bf16)a0.z; f0[3] = (__bf16)a0.w;
                f0[4] = (__bf16)a1.x; f0[5] = (__bf16)a1.y;
                f0[6] = (__bf16)a1.z; f0[7] = (__bf16)a1.w;
                f1[0] = (__bf16)b0.x; f1[1] = (__bf16)b0.y;
                f1[2] = (__bf16)b0.z; f1[3] = (__bf16)b0.w;
                f1[4] = (__bf16)b1.x; f1[5] = (__bf16)b1.y;
                f1[6] = (__bf16)b1.z; f1[7] = (__bf16)b1.w;
                xf[st][0] = f0;
                xf[st][1] = f1;
            }
        }

        float m[TPW], s[TPW];
        #pragma unroll
        for (int st = 0; st < TPW; ++st) { m[st] = -INFINITY; s[st] = 0.0f; }

        #pragma unroll 2
        for (int ii = 0; ii < NC; ++ii) {
            const int kk = (ii + w) & (NC - 1);      // per-wave stagger
            float mah[TPW];
            #pragma unroll
            for (int st = 0; st < TPW; ++st) mah[st] = 0.0f;

            const char* gk = gbuf + kk * 8192;
            const float* ntk = &nt_lds[kk * NF];

            // rc 0,1: rows 0..31 of lower-tri G -> cols 32..63 are ZERO
            #pragma unroll
            for (int rc = 0; rc < 2; ++rc) {
                bf16x8 ga = *(const bf16x8*)(gk + offA[rc]);
                f32x4 ntv = *(const f32x4*)(ntk + rc * 16 + lg * 4);
                #pragma unroll
                for (int st = 0; st < TPW; ++st) {
                    f32x4 acc = ntv;
                    acc = __builtin_amdgcn_mfma_f32_16x16x32_bf16(ga, xf[st][0], acc, 0, 0, 0);
                    mah[st] = fmaf(acc[0], acc[0], mah[st]);
                    mah[st] = fmaf(acc[1], acc[1], mah[st]);
                    mah[st] = fmaf(acc[2], acc[2], mah[st]);
                    mah[st] = fmaf(acc[3], acc[3], mah[st]);
                }
            }
            // rc 2,3: full rows
            #pragma unroll
            for (int rc = 2; rc < 4; ++rc) {
                bf16x8 ga = *(const bf16x8*)(gk + offA[rc]);
                bf16x8 gb = *(const bf16x8*)(gk + offB[rc]);
                f32x4 ntv = *(const f32x4*)(ntk + rc * 16 + lg * 4);
                #pragma unroll
                for (int st = 0; st < TPW; ++st) {
                    f32x4 acc = ntv;
                    acc = __builtin_amdgcn_mfma_f32_16x16x32_bf16(ga, xf[st][0], acc, 0, 0, 0);
                    acc = __builtin_amdgcn_mfma_f32_16x16x32_bf16(gb, xf[st][1], acc, 0, 0, 0);
                    mah[st] = fmaf(acc[0], acc[0], mah[st]);
                    mah[st] = fmaf(acc[1], acc[1], mah[st]);
                    mah[st] = fmaf(acc[2], acc[2], mah[st]);
                    mah[st] = fmaf(acc[3], acc[3], mah[st]);
                }
            }

            // defer-max logsumexp
            float Ck = cc_lds[kk];
            float wlp[TPW];
            float dmax = -INFINITY;
            #pragma unroll
            for (int st = 0; st < TPW; ++st) {
                float v = mah[st];
                v += __shfl_xor(v, 16);
                v += __shfl_xor(v, 32);          // all lanes hold full maha
                wlp[st] = fmaf(-0.5f, v, Ck);
                dmax = fmaxf(dmax, wlp[st] - m[st]);
            }
            if (__any(dmax > 60.0f)) {           // rare after first comp
                #pragma unroll
                for (int st = 0; st < TPW; ++st) {
                    float mn = fmaxf(m[st], wlp[st]);
                    s[st] = s[st] * __expf(m[st] - mn) + __expf(wlp[st] - mn);
                    m[st] = mn;
                }
            } else {                             // common: 1 exp + 1 add
                #pragma unroll
                for (int st = 0; st < TPW; ++st)
                    s[st] += __expf(wlp[st] - m[st]);
            }
        }

        if (lg == 0) {
            #pragma unroll
            for (int st = 0; st < TPW; ++st) {
                long sid = base + st * 16 + l15;
                if (sid < (long)N)
                    wavePartial += m[st] + __logf(s[st]);
            }
        }
    }

    #pragma unroll
    for (int off = 1; off < 64; off <<= 1)
        wavePartial += __shfl_xor(wavePartial, off);
    if (lane == 0)
        partials[gid] = wavePartial;
}

// ---------------------------------------------------------------------------
// Kernel 3: deterministic final reduction over per-wave partials.
// ---------------------------------------------------------------------------
__global__ __launch_bounds__(256) void gmm_reduce(
    const float* __restrict__ partials, int n, float* __restrict__ out)
{
    float s = 0.0f;
    for (int i = threadIdx.x; i < n; i += 256)
        s += partials[i];
    #pragma unroll
    for (int off = 1; off < 64; off <<= 1)
        s += __shfl_xor(s, off);
    __shared__ float sm[4];
    const int wave = threadIdx.x >> 6;
    const int lane = threadIdx.x & 63;
    if (lane == 0) sm[wave] = s;
    __syncthreads();
    if (threadIdx.x == 0)
        out[0] = (sm[0] + sm[1]) + (sm[2] + sm[3]);
}

// ---------------------------------------------------------------------------
extern "C" void kernel_launch(void* const* d_in, const int* in_sizes, int n_in,
                              void* d_out, int out_size, void* d_ws, size_t ws_size,
                              hipStream_t stream)
{
    const float* data    = (const float*)d_in[0];
    const float* weights = (const float*)d_in[1];
    const float* means   = (const float*)d_in[2];
    const float* cov     = (const float*)d_in[3];

    const int N = in_sizes[0] / NF;

    char* ws = (char*)d_ws;
    __hip_bfloat16* g = (__hip_bfloat16*)ws;                    // 131072 B (swizzled)
    float* t          = (float*)(ws + 131072);                  // 4096 B
    float* Cc         = (float*)(ws + 131072 + 4096);           // 64 B
    float* partials   = (float*)(ws + 131072 + 4096 + 64);      // totalWaves * 4 B

    const int nTiles     = (N + TPW * 16 - 1) / (TPW * 16);
    const int totalWaves = MAIN_BLOCKS * MAIN_WAVES;

    gmm_precompute<<<NC, 256, 0, stream>>>(cov, means, weights, g, t, Cc);
    gmm_main<<<MAIN_BLOCKS, 64 * MAIN_WAVES, 0, stream>>>(
        data, (const char*)g, t, Cc, partials, nTiles, N, totalWaves);
    gmm_reduce<<<1, 256, 0, stream>>>(partials, totalWaves, (float*)d_out);
}

// Round 21
// 60.364 us; speedup vs baseline: 2.0272x; 1.0311x over previous
//
#include <hip/hip_runtime.h>
#include <hip/hip_bf16.h>
#include <math.h>

#define NF 64
#define NC 16
#define MAIN_BLOCKS 250
#define MAIN_WAVES  10                 // 640 thr; 2500 waves == 2500 tiles EXACTLY
#define TPW 5                          // 16-sample subtiles per wave (80 samples)

typedef __bf16 bf16x8 __attribute__((ext_vector_type(8)));
typedef float f32x4 __attribute__((ext_vector_type(4)));
typedef unsigned int u32;

// async global->LDS, 16B/lane. LDS dest = wave-uniform base (HW adds lane*16).
__device__ __forceinline__ void stage16(const void* gsrc, void* ldst) {
    __builtin_amdgcn_global_load_lds(
        (const __attribute__((address_space(1))) u32*)gsrc,
        (__attribute__((address_space(3))) u32*)ldst,
        16, 0, 0);
}

// ---------------------------------------------------------------------------
// Kernel 1 v20 (unchanged): RANK-2 fused Cholesky + inverse, 32 rounds.
// ---------------------------------------------------------------------------
__global__ __launch_bounds__(256) void gmm_precompute(
    const float* __restrict__ cov,
    const float* __restrict__ means,
    const float* __restrict__ weights,
    __hip_bfloat16* __restrict__ g,
    float* __restrict__ t,
    float* __restrict__ Cc)
{
    const int w = threadIdx.x >> 6;   // wave 0..3: rows [16w,16w+16)
    const int c = threadIdx.x & 63;   // lane owns column c
    const int k = blockIdx.x;

    __shared__ __align__(16) float LT[NF][68];   // LT[j][r] = L[r][j]
    __shared__ float Xs[NF][65];                 // Xs[i][c] = G[i][c]
    __shared__ __align__(16) float wbA2[2][68];
    __shared__ __align__(16) float wbB2[2][68];
    __shared__ __align__(16) float gwA2[2][68];
    __shared__ __align__(16) float gwB2[2][68];

    float a_loc[16];
    {
        const float* src = cov + (long)k * NF * NF + (w * 16) * NF + c;
        #pragma unroll
        for (int r = 0; r < 16; ++r)
            a_loc[r] = src[r * NF];
    }

    float s_loc[16];
    #pragma unroll
    for (int r = 0; r < 16; ++r)
        s_loc[r] = (w * 16 + r == c) ? 1.0f : 0.0f;

    float logdiag = 0.0f;
    float gvA = 0.0f, gvB = 0.0f;     // owner wave's pending G rows

    #pragma unroll 1
    for (int q = 0; q < 4; ++q) {
        #pragma unroll
        for (int h = 0; h < 8; ++h) {          // round r = q*8+h; steps j, j+1
            const int j = q * 16 + 2 * h;
            float* wbA = wbA2[h & 1];
            float* wbB = wbB2[h & 1];
            float* gwA = gwA2[h & 1];
            float* gwB = gwB2[h & 1];

            if (w == q) {                       // publish A rows j, j+1
                wbA[c] = a_loc[2 * h];
                wbB[c] = a_loc[2 * h + 1];
            }
            if (j > 0) {                        // publish G rows j-2, j-1
                const int pw = (h == 0) ? (q - 1) : q;
                if (w == pw) {
                    gwA[c] = gvA;  Xs[j - 2][c] = gvA;
                    gwB[c] = gvB;  Xs[j - 1][c] = gvB;
                }
            }
            __syncthreads();

            // ---- Cholesky steps j, j+1 ----
            float ajc = wbA[c];
            float bjc = wbB[c];
            float d0  = wbA[j];
            float a1j = wbA[j + 1];
            float b1j = wbB[j + 1];
            float rd0 = __builtin_amdgcn_rcpf(d0);
            float k0  = a1j * rd0;
            float d1  = fmaf(-a1j, k0, b1j);
            float rd1 = __builtin_amdgcn_rcpf(d1);
            float rsq0 = __builtin_amdgcn_rcpf(sqrtf(d0));
            float rsq1 = __builtin_amdgcn_rcpf(sqrtf(d1));
            logdiag += 0.5f * (__logf(d0) + __logf(d1));
            float w1c = fmaf(-ajc, k0, bjc);
            LT[j][c]     = ajc * rsq0;
            LT[j + 1][c] = w1c * rsq1;
            float beta0 = ajc * rd0;
            float beta1 = w1c * rd1;
            {
                const float4* wvA = (const float4*)(wbA + w * 16);
                const float4* wvB = (const float4*)(wbB + w * 16);
                #pragma unroll
                for (int rr = 0; rr < 16; rr += 4) {
                    float4 vA = wvA[rr >> 2];
                    float4 vB = wvB[rr >> 2];
                    float t0 = fmaf(-vA.x, k0, vB.x);
                    float t1 = fmaf(-vA.y, k0, vB.y);
                    float t2 = fmaf(-vA.z, k0, vB.z);
                    float t3 = fmaf(-vA.w, k0, vB.w);
                    a_loc[rr]     = fmaf(-t0, beta1, fmaf(-vA.x, beta0, a_loc[rr]));
                    a_loc[rr + 1] = fmaf(-t1, beta1, fmaf(-vA.y, beta0, a_loc[rr + 1]));
                    a_loc[rr + 2] = fmaf(-t2, beta1, fmaf(-vA.z, beta0, a_loc[rr + 2]));
                    a_loc[rr + 3] = fmaf(-t3, beta1, fmaf(-vA.w, beta0, a_loc[rr + 3]));
                }
            }

            // ---- substitution steps j-2, j-1 ----
            if (j > 0) {
                float gA = gwA[c];
                float gB = gwB[c];
                const float4* lvA = (const float4*)(&LT[j - 2][w * 16]);
                const float4* lvB = (const float4*)(&LT[j - 1][w * 16]);
                #pragma unroll
                for (int rr = 0; rr < 16; rr += 4) {
                    float4 vA = lvA[rr >> 2];
                    float4 vB = lvB[rr >> 2];
                    s_loc[rr]     = fmaf(-vB.x, gB, fmaf(-vA.x, gA, s_loc[rr]));
                    s_loc[rr + 1] = fmaf(-vB.y, gB, fmaf(-vA.y, gA, s_loc[rr + 1]));
                    s_loc[rr + 2] = fmaf(-vB.z, gB, fmaf(-vA.z, gA, s_loc[rr + 2]));
                    s_loc[rr + 3] = fmaf(-vB.w, gB, fmaf(-vA.w, gA, s_loc[rr + 3]));
                }
            }

            // ---- end of round: owner computes G rows j, j+1 ----
            if (w == q) {
                float l10 = a1j * rsq0;
                gvA = s_loc[2 * h] * rsq0;
                gvB = fmaf(-l10, gvA, s_loc[2 * h + 1]) * rsq1;
            }
        }
    }

    if (w == 3) { Xs[62][c] = gvA; Xs[63][c] = gvB; }
    __syncthreads();

    // g row c: chunks jb=2w,2w+1, XOR-swizzled (jb ^ (row&7))
    {
        __hip_bfloat16* grow = g + ((long)(k * NF + c)) * NF;
        #pragma unroll
        for (int h = 0; h < 2; ++h) {
            int jb = w * 2 + h;
            bf16x8 v;
            #pragma unroll
            for (int u = 0; u < 8; ++u)
                v[u] = (__bf16)Xs[c][jb * 8 + u];
            *(bf16x8*)(grow + ((jb ^ (c & 7)) * 8)) = v;
        }
    }

    if (w == 0) {
        const float* mu = means + k * NF;
        float a0 = 0.0f, a1 = 0.0f;
        #pragma unroll
        for (int j = 0; j < NF; j += 2) {
            a0 = fmaf(Xs[c][j],     mu[j],     a0);
            a1 = fmaf(Xs[c][j + 1], mu[j + 1], a1);
        }
        t[k * NF + c] = a0 + a1;
        if (c == 0)
            Cc[k] = __logf(weights[k]) - 0.5f * (float)NF * 1.8378770664093453f - logdiag;
    }
}

// ---------------------------------------------------------------------------
// Kernel 2 v21: v16/v20 body at TPW=5, 10 waves/block, 250 blocks:
// 2500 waves == 2500 tiles EXACTLY (100% balance, no grid-stride tail),
// and the 14 G/nt ds_reads per comp amortize over 80 samples (-20% DS,
// the largest pipe). Swizzle/tri-skip/stagger/defer-max unchanged.
// ---------------------------------------------------------------------------
__global__ __launch_bounds__(640) void gmm_main(
    const float* __restrict__ data,
    const char* __restrict__ gsw,         // swizzled bf16 G, [NC][8192 B]
    const float* __restrict__ t,
    const float* __restrict__ Cc,
    float* __restrict__ partials,
    int nTiles, int N, int totalWaves)
{
    __shared__ __align__(16) char gbuf[NC * 8192];   // 128 KiB
    __shared__ __align__(16) float nt_lds[NC * NF];  // negated t
    __shared__ float cc_lds[NC];

    const int tidx = threadIdx.x;
    const int w    = tidx >> 6;
    const int lane = tidx & 63;
    const int l15  = lane & 15;
    const int lg   = lane >> 4;

    // stage G: wave w covers comps {w, w+10} (<16)
    for (int i = w; i < NC; i += MAIN_WAVES) {
        const char* src = gsw + (size_t)i * 8192;
        char* dst = gbuf + (size_t)i * 8192;
        #pragma unroll
        for (int u = 0; u < 8; ++u)
            stage16(src + u * 1024 + lane * 16, dst + u * 1024);
    }

    for (int i = tidx; i < NC * NF; i += 64 * MAIN_WAVES) nt_lds[i] = -t[i];
    if (tidx < NC) cc_lds[tidx] = Cc[tidx];

    const int gid = blockIdx.x * MAIN_WAVES + w;

    // swizzled LDS byte offsets (static per lane)
    int offA[4], offB[4];
    #pragma unroll
    for (int rc = 0; rc < 4; ++rc) {
        int row = rc * 16 + l15;
        offA[rc] = row * 128 + ((lg       ^ (l15 & 7)) * 16);
        offB[rc] = row * 128 + (((lg + 4) ^ (l15 & 7)) * 16);
    }

    // first tile's x fragments (overlaps the staging flight)
    bf16x8 xf[TPW][2];
    if (gid < nTiles) {
        const long base = (long)gid * (TPW * 16);
        #pragma unroll
        for (int st = 0; st < TPW; ++st) {
            long row = base + st * 16 + l15;
            if (row > (long)N - 1) row = (long)N - 1;
            const float* xp = data + row * NF + lg * 8;
            float4 a0 = *(const float4*)(xp);
            float4 a1 = *(const float4*)(xp + 4);
            float4 b0 = *(const float4*)(xp + 32);
            float4 b1 = *(const float4*)(xp + 36);
            bf16x8 f0, f1;
            f0[0] = (__bf16)a0.x; f0[1] = (__bf16)a0.y;
            f0[2] = (__bf16)a0.z; f0[3] = (__bf16)a0.w;
            f0[4] = (__bf16)a1.x; f0[5] = (__bf16)a1.y;
            f0[6] = (__bf16)a1.z; f0[7] = (__bf16)a1.w;
            f1[0] = (__bf16)b0.x; f1[1] = (__bf16)b0.y;
            f1[2] = (__bf16)b0.z; f1[3] = (__bf16)b0.w;
            f1[4] = (__bf16)b1.x; f1[5] = (__bf16)b1.y;
            f1[6] = (__bf16)b1.z; f1[7] = (__bf16)b1.w;
            xf[st][0] = f0;
            xf[st][1] = f1;
        }
    }

    __syncthreads();   // G + t staged; only barrier in the kernel

    float wavePartial = 0.0f;

    #pragma unroll 1
    for (int tile = gid; tile < nTiles; tile += totalWaves) {
        const long base = (long)tile * (TPW * 16);
        if (tile != gid) {     // unreachable at N=200000 (exact balance)
            #pragma unroll
            for (int st = 0; st < TPW; ++st) {
                long row = base + st * 16 + l15;
                if (row > (long)N - 1) row = (long)N - 1;
                const float* xp = data + row * NF + lg * 8;
                float4 a0 = *(const float4*)(xp);
                float4 a1 = *(const float4*)(xp + 4);
                float4 b0 = *(const float4*)(xp + 32);
                float4 b1 = *(const float4*)(xp + 36);
                bf16x8 f0, f1;
                f0[0] = (__bf16)a0.x; f0[1] = (__bf16)a0.y;
                f0[2] = (__bf16)a0.z; f0[3] = (__bf16)a0.w;
                f0[4] = (__bf16)a1.x; f0[5] = (__bf16)a1.y;
                f0[6] = (__bf16)a1.z; f0[7] = (__bf16)a1.w;
                f1[0] = (__bf16)b0.x; f1[1] = (__bf16)b0.y;
                f1[2] = (__bf16)b0.z; f1[3] = (__bf16)b0.w;
                f1[4] = (__bf16)b1.x; f1[5] = (__bf16)b1.y;
                f1[6] = (__bf16)b1.z; f1[7] = (__bf16)b1.w;
                xf[st][0] = f0;
                xf[st][1] = f1;
            }
        }

        float m[TPW], s[TPW];
        #pragma unroll
        for (int st = 0; st < TPW; ++st) { m[st] = -INFINITY; s[st] = 0.0f; }

        #pragma unroll 2
        for (int ii = 0; ii < NC; ++ii) {
            const int kk = (ii + w) & (NC - 1);      // per-wave stagger
            float mah[TPW];
            #pragma unroll
            for (int st = 0; st < TPW; ++st) mah[st] = 0.0f;

            const char* gk = gbuf + kk * 8192;
            const float* ntk = &nt_lds[kk * NF];

            // rc 0,1: rows 0..31 of lower-tri G -> cols 32..63 are ZERO
            #pragma unroll
            for (int rc = 0; rc < 2; ++rc) {
                bf16x8 ga = *(const bf16x8*)(gk + offA[rc]);
                f32x4 ntv = *(const f32x4*)(ntk + rc * 16 + lg * 4);
                #pragma unroll
                for (int st = 0; st < TPW; ++st) {
                    f32x4 acc = ntv;
                    acc = __builtin_amdgcn_mfma_f32_16x16x32_bf16(ga, xf[st][0], acc, 0, 0, 0);
                    mah[st] = fmaf(acc[0], acc[0], mah[st]);
                    mah[st] = fmaf(acc[1], acc[1], mah[st]);
                    mah[st] = fmaf(acc[2], acc[2], mah[st]);
                    mah[st] = fmaf(acc[3], acc[3], mah[st]);
                }
            }
            // rc 2,3: full rows
            #pragma unroll
            for (int rc = 2; rc < 4; ++rc) {
                bf16x8 ga = *(const bf16x8*)(gk + offA[rc]);
                bf16x8 gb = *(const bf16x8*)(gk + offB[rc]);
                f32x4 ntv = *(const f32x4*)(ntk + rc * 16 + lg * 4);
                #pragma unroll
                for (int st = 0; st < TPW; ++st) {
                    f32x4 acc = ntv;
                    acc = __builtin_amdgcn_mfma_f32_16x16x32_bf16(ga, xf[st][0], acc, 0, 0, 0);
                    acc = __builtin_amdgcn_mfma_f32_16x16x32_bf16(gb, xf[st][1], acc, 0, 0, 0);
                    mah[st] = fmaf(acc[0], acc[0], mah[st]);
                    mah[st] = fmaf(acc[1], acc[1], mah[st]);
                    mah[st] = fmaf(acc[2], acc[2], mah[st]);
                    mah[st] = fmaf(acc[3], acc[3], mah[st]);
                }
            }

            // defer-max logsumexp
            float Ck = cc_lds[kk];
            float wlp[TPW];
            float dmax = -INFINITY;
            #pragma unroll
            for (int st = 0; st < TPW; ++st) {
                float v = mah[st];
                v += __shfl_xor(v, 16);
                v += __shfl_xor(v, 32);          // all lanes hold full maha
                wlp[st] = fmaf(-0.5f, v, Ck);
                dmax = fmaxf(dmax, wlp[st] - m[st]);
            }
            if (__any(dmax > 60.0f)) {           // rare after first comp
                #pragma unroll
                for (int st = 0; st < TPW; ++st) {
                    float mn = fmaxf(m[st], wlp[st]);
                    s[st] = s[st] * __expf(m[st] - mn) + __expf(wlp[st] - mn);
                    m[st] = mn;
                }
            } else {                             // common: 1 exp + 1 add
                #pragma unroll
                for (int st = 0; st < TPW; ++st)
                    s[st] += __expf(wlp[st] - m[st]);
            }
        }

        if (lg == 0) {
            #pragma unroll
            for (int st = 0; st < TPW; ++st) {
                long sid = base + st * 16 + l15;
                if (sid < (long)N)
                    wavePartial += m[st] + __logf(s[st]);
            }
        }
    }

    #pragma unroll
    for (int off = 1; off < 64; off <<= 1)
        wavePartial += __shfl_xor(wavePartial, off);
    if (lane == 0)
        partials[gid] = wavePartial;
}

// ---------------------------------------------------------------------------
// Kernel 3: deterministic final reduction over per-wave partials.
// ---------------------------------------------------------------------------
__global__ __launch_bounds__(256) void gmm_reduce(
    const float* __restrict__ partials, int n, float* __restrict__ out)
{
    float s = 0.0f;
    for (int i = threadIdx.x; i < n; i += 256)
        s += partials[i];
    #pragma unroll
    for (int off = 1; off < 64; off <<= 1)
        s += __shfl_xor(s, off);
    __shared__ float sm[4];
    const int wave = threadIdx.x >> 6;
    const int lane = threadIdx.x & 63;
    if (lane == 0) sm[wave] = s;
    __syncthreads();
    if (threadIdx.x == 0)
        out[0] = (sm[0] + sm[1]) + (sm[2] + sm[3]);
}

// ---------------------------------------------------------------------------
extern "C" void kernel_launch(void* const* d_in, const int* in_sizes, int n_in,
                              void* d_out, int out_size, void* d_ws, size_t ws_size,
                              hipStream_t stream)
{
    const float* data    = (const float*)d_in[0];
    const float* weights = (const float*)d_in[1];
    const float* means   = (const float*)d_in[2];
    const float* cov     = (const float*)d_in[3];

    const int N = in_sizes[0] / NF;

    char* ws = (char*)d_ws;
    __hip_bfloat16* g = (__hip_bfloat16*)ws;                    // 131072 B (swizzled)
    float* t          = (float*)(ws + 131072);                  // 4096 B
    float* Cc         = (float*)(ws + 131072 + 4096);           // 64 B
    float* partials   = (float*)(ws + 131072 + 4096 + 64);      // totalWaves * 4 B

    const int nTiles     = (N + TPW * 16 - 1) / (TPW * 16);
    const int totalWaves = MAIN_BLOCKS * MAIN_WAVES;

    gmm_precompute<<<NC, 256, 0, stream>>>(cov, means, weights, g, t, Cc);
    gmm_main<<<MAIN_BLOCKS, 64 * MAIN_WAVES, 0, stream>>>(
        data, (const char*)g, t, Cc, partials, nTiles, N, totalWaves);
    gmm_reduce<<<1, 256, 0, stream>>>(partials, totalWaves, (float*)d_out);
}